// Round 6
// baseline (945.980 us; speedup 1.0000x reference)
//
#include <hip/hip_runtime.h>
#include <hip/hip_bf16.h>

typedef __bf16 bf16;
typedef __attribute__((ext_vector_type(8))) __bf16 bf16x8;
typedef __attribute__((ext_vector_type(4))) __bf16 bf16x4;
typedef __attribute__((ext_vector_type(4))) float f32x4;

// ---------------------------------------------------------------- convert
__global__ void cvt_f32_bf16(const float* __restrict__ in,
                             bf16* __restrict__ out, long n) {
  long i = ((long)blockIdx.x * blockDim.x + threadIdx.x) * 8;
  if (i >= n) return;
  f32x4 a = *reinterpret_cast<const f32x4*>(in + i);
  f32x4 b = *reinterpret_cast<const f32x4*>(in + i + 4);
  bf16x8 o;
  o[0] = (bf16)a[0]; o[1] = (bf16)a[1]; o[2] = (bf16)a[2]; o[3] = (bf16)a[3];
  o[4] = (bf16)b[0]; o[5] = (bf16)b[1]; o[6] = (bf16)b[2]; o[7] = (bf16)b[3];
  *reinterpret_cast<bf16x8*>(out + i) = o;
}

// ---------------------------------------------------------------- GEMM
// C[M][N] = A[M][K] (bf16) * B[N][K]^T (fp32, converted in staging)
// 128x128 tile, 4 waves (2x2 of 64x64), 16x16x32 bf16 MFMA, single-buffered.
// CT = output element type (bf16 for intermediates, float for d_out).
template <typename CT>
__global__ __launch_bounds__(256)
void gemm_bt(const bf16* __restrict__ A, const float* __restrict__ B,
             CT* __restrict__ C, int M, int N, int K) {
  __shared__ __align__(16) bf16 As[128 * 32];
  __shared__ __align__(16) bf16 Bs[128 * 32];
  const int t = threadIdx.x;
  const int lane = t & 63;
  const int w = t >> 6;
  const int wr = w >> 1, wc = w & 1;
  const int bm = blockIdx.y * 128, bn = blockIdx.x * 128;
  const int fr = lane & 15, fg = lane >> 4;
  const int srow = t >> 3;         // 0..31
  const int scol = (t & 7) * 4;    // 0,4,..,28

  f32x4 acc[4][4];
#pragma unroll
  for (int m = 0; m < 4; m++)
#pragma unroll
    for (int n = 0; n < 4; n++) acc[m][n] = (f32x4){0.f, 0.f, 0.f, 0.f};

  for (int k0 = 0; k0 < K; k0 += 32) {
    __syncthreads();  // previous iteration's LDS reads complete
#pragma unroll
    for (int p = 0; p < 4; p++) {
      const int r = srow + p * 32;
      bf16x4 a4 = *reinterpret_cast<const bf16x4*>(&A[(long)(bm + r) * K + k0 + scol]);
      f32x4 b4 = *reinterpret_cast<const f32x4*>(&B[(long)(bn + r) * K + k0 + scol]);
      bf16x4 bb;
      bb[0] = (bf16)b4[0]; bb[1] = (bf16)b4[1];
      bb[2] = (bf16)b4[2]; bb[3] = (bf16)b4[3];
      *reinterpret_cast<bf16x4*>(&As[r * 32 + scol]) = a4;
      *reinterpret_cast<bf16x4*>(&Bs[r * 32 + scol]) = bb;
    }
    __syncthreads();  // tile staged

    bf16x8 af[4], bfr[4];
#pragma unroll
    for (int m = 0; m < 4; m++)
      af[m] = *reinterpret_cast<const bf16x8*>(
          &As[(wr * 64 + m * 16 + fr) * 32 + fg * 8]);
#pragma unroll
    for (int n = 0; n < 4; n++)
      bfr[n] = *reinterpret_cast<const bf16x8*>(
          &Bs[(wc * 64 + n * 16 + fr) * 32 + fg * 8]);
#pragma unroll
    for (int m = 0; m < 4; m++)
#pragma unroll
      for (int n = 0; n < 4; n++)
        acc[m][n] =
            __builtin_amdgcn_mfma_f32_16x16x32_bf16(af[m], bfr[n], acc[m][n], 0, 0, 0);
  }

#pragma unroll
  for (int m = 0; m < 4; m++) {
#pragma unroll
    for (int n = 0; n < 4; n++) {
      const int row0 = bm + wr * 64 + m * 16 + fg * 4;
      const int col = bn + wc * 64 + n * 16 + fr;
#pragma unroll
      for (int j = 0; j < 4; j++)
        C[(long)(row0 + j) * N + col] = (CT)acc[m][n][j];
    }
  }
}

// ---------------------------------------------------------------- RoPE
// q: (2048, 32*128), k: (2048, 8*128); in-place, fp32 math
__global__ void rope_kernel(bf16* __restrict__ q, bf16* __restrict__ k,
                            const int* __restrict__ pos_ids) {
  int idx = blockIdx.x * blockDim.x + threadIdx.x;  // 2048*40*64
  int s = idx / 2560;
  int rem = idx % 2560;
  int hh = rem >> 6;
  int dp = rem & 63;
  float p = (float)pos_ids[s];
  // inv_freq = 10000^(-dp/64) = exp2(-dp * log2(10000)/64)
  float freq = p * exp2f(-(float)dp * 0.20762050593046025f);
  float cs, sn;
  sincosf(freq, &sn, &cs);
  bf16* base = (hh < 32) ? (q + (long)s * 4096 + hh * 128)
                         : (k + (long)s * 1024 + (hh - 32) * 128);
  float x1 = (float)base[dp], x2 = (float)base[dp + 64];
  base[dp] = (bf16)(x1 * cs - x2 * sn);
  base[dp + 64] = (bf16)(x2 * cs + x1 * sn);
}

// ---------------------------------------------------------------- attention
// q:(2048,4096) k,v:(2048,1024) out:(2048,4096), GQA 4:1, causal
__global__ __launch_bounds__(256)
void attn_fwd(const bf16* __restrict__ qg, const bf16* __restrict__ kg,
              const bf16* __restrict__ vg, bf16* __restrict__ og) {
  const int h = blockIdx.y;
  const int q0 = blockIdx.x * 64;
  const int kvh = h >> 2;
  __shared__ __align__(16) bf16 Ks[32 * 128];    // [kv][d]
  __shared__ __align__(16) bf16 Vt[128 * 40];    // [d][kv], pitch 40
  __shared__ __align__(16) bf16 Pl[4][16 * 40];  // per-wave P, pitch 40
  const int t = threadIdx.x, lane = t & 63, w = t >> 6;
  const int fr = lane & 15, fg = lane >> 4;
  const int qrow = q0 + w * 16 + fr;

  bf16x8 aq[4];
#pragma unroll
  for (int c = 0; c < 4; c++)
    aq[c] = *reinterpret_cast<const bf16x8*>(
        &qg[(long)qrow * 4096 + h * 128 + c * 32 + fg * 8]);

  f32x4 oacc[8];
#pragma unroll
  for (int n = 0; n < 8; n++) oacc[n] = (f32x4){0.f, 0.f, 0.f, 0.f};
  float mrow[4], lrow[4];
#pragma unroll
  for (int j = 0; j < 4; j++) { mrow[j] = -INFINITY; lrow[j] = 0.f; }
  const float scale = 0.08838834764831845f;

  const int krow = t >> 3, kcol = (t & 7) * 16;  // K staging map
  const int vkv = t & 31, vdb = (t >> 5) * 16;   // V staging map

  for (int kv0 = 0; kv0 < q0 + 64; kv0 += 32) {
    {  // stage K tile [32][128], reg-staged
      const bf16* gk = &kg[(long)(kv0 + krow) * 1024 + kvh * 128 + kcol];
      bf16x8 ka = *reinterpret_cast<const bf16x8*>(gk);
      bf16x8 kb = *reinterpret_cast<const bf16x8*>(gk + 8);
      *reinterpret_cast<bf16x8*>(&Ks[krow * 128 + kcol]) = ka;
      *reinterpret_cast<bf16x8*>(&Ks[krow * 128 + kcol + 8]) = kb;
    }
    {  // stage V transposed: Vt[d][kv]
      const bf16* gv = &vg[(long)(kv0 + vkv) * 1024 + kvh * 128 + vdb];
      bf16x8 va = *reinterpret_cast<const bf16x8*>(gv);
      bf16x8 vb = *reinterpret_cast<const bf16x8*>(gv + 8);
#pragma unroll
      for (int j = 0; j < 8; j++) {
        Vt[(vdb + j) * 40 + vkv] = va[j];
        Vt[(vdb + 8 + j) * 40 + vkv] = vb[j];
      }
    }
    __syncthreads();

    // S = Q K^T  (16 q-rows x 32 kv)
    f32x4 sacc[2];
    sacc[0] = (f32x4){0.f, 0.f, 0.f, 0.f};
    sacc[1] = (f32x4){0.f, 0.f, 0.f, 0.f};
#pragma unroll
    for (int c = 0; c < 2; c++)
#pragma unroll
      for (int kc = 0; kc < 4; kc++) {
        bf16x8 bk = *reinterpret_cast<const bf16x8*>(
            &Ks[(c * 16 + fr) * 128 + kc * 32 + fg * 8]);
        sacc[c] = __builtin_amdgcn_mfma_f32_16x16x32_bf16(aq[kc], bk, sacc[c], 0, 0, 0);
      }

    // online softmax (rows live in 16-lane groups)
    float pv[2][4];
#pragma unroll
    for (int j = 0; j < 4; j++) {
      const int qp = q0 + w * 16 + fg * 4 + j;
      float s0 = sacc[0][j] * scale, s1 = sacc[1][j] * scale;
      if (kv0 + fr > qp) s0 = -INFINITY;
      if (kv0 + 16 + fr > qp) s1 = -INFINITY;
      float rmax = fmaxf(s0, s1);
#pragma unroll
      for (int off = 1; off < 16; off <<= 1)
        rmax = fmaxf(rmax, __shfl_xor(rmax, off, 64));
      float mnew = fmaxf(mrow[j], rmax);
      float alpha = __expf(mrow[j] - mnew);
      mrow[j] = mnew;
      float p0 = __expf(s0 - mnew), p1 = __expf(s1 - mnew);
      float rsum = p0 + p1;
#pragma unroll
      for (int off = 1; off < 16; off <<= 1) rsum += __shfl_xor(rsum, off, 64);
      lrow[j] = lrow[j] * alpha + rsum;
#pragma unroll
      for (int n = 0; n < 8; n++) oacc[n][j] *= alpha;
      pv[0][j] = p0; pv[1][j] = p1;
    }
    // P -> LDS (bf16), repack into A-fragment layout
#pragma unroll
    for (int j = 0; j < 4; j++) {
      Pl[w][(fg * 4 + j) * 40 + fr] = (bf16)pv[0][j];
      Pl[w][(fg * 4 + j) * 40 + 16 + fr] = (bf16)pv[1][j];
    }
    bf16x8 ap = *reinterpret_cast<const bf16x8*>(&Pl[w][fr * 40 + fg * 8]);
#pragma unroll
    for (int n = 0; n < 8; n++) {
      bf16x8 bv = *reinterpret_cast<const bf16x8*>(&Vt[(n * 16 + fr) * 40 + fg * 8]);
      oacc[n] = __builtin_amdgcn_mfma_f32_16x16x32_bf16(ap, bv, oacc[n], 0, 0, 0);
    }
    __syncthreads();
  }

#pragma unroll
  for (int n = 0; n < 8; n++) {
#pragma unroll
    for (int j = 0; j < 4; j++) {
      const int row = q0 + w * 16 + fg * 4 + j;
      const int col = h * 128 + n * 16 + fr;
      og[(long)row * 4096 + col] = (bf16)(oacc[n][j] / lrow[j]);
    }
  }
}

// ---------------------------------------------------------------- launch
extern "C" void kernel_launch(void* const* d_in, const int* in_sizes, int n_in,
                              void* d_out, int out_size, void* d_ws,
                              size_t ws_size, hipStream_t stream) {
  const float* hs = (const float*)d_in[0];
  const int* pos = (const int*)d_in[2];
  const float* Wq = (const float*)d_in[3];
  const float* Wk = (const float*)d_in[4];
  const float* Wv = (const float*)d_in[5];
  const float* Wo = (const float*)d_in[6];

  // ws layout (40 MB total):
  //   q_bf  [ 0,16M)   k_bf [16M,20M)   v_bf [20M,24M)
  //   h_bf  [24M,40M)  -- dead after V projection; at_bf aliases it
  char* ws = (char*)d_ws;
  bf16* q_bf  = (bf16*)(ws);
  bf16* k_bf  = (bf16*)(ws + 16777216L);
  bf16* v_bf  = (bf16*)(ws + 20971520L);
  bf16* h_bf  = (bf16*)(ws + 25165824L);
  bf16* at_bf = h_bf;  // alias: h_bf last read before attn writes at_bf

  cvt_f32_bf16<<<dim3(4096), 256, 0, stream>>>(hs, h_bf, 8388608L);

  gemm_bt<bf16><<<dim3(32, 16), 256, 0, stream>>>(h_bf, Wq, q_bf, 2048, 4096, 4096);
  gemm_bt<bf16><<<dim3(8, 16), 256, 0, stream>>>(h_bf, Wk, k_bf, 2048, 1024, 4096);
  gemm_bt<bf16><<<dim3(8, 16), 256, 0, stream>>>(h_bf, Wv, v_bf, 2048, 1024, 4096);

  rope_kernel<<<dim3(20480), 256, 0, stream>>>(q_bf, k_bf, pos);

  attn_fwd<<<dim3(32, 32), 256, 0, stream>>>(q_bf, k_bf, v_bf, at_bf);

  // d_out is FLOAT32 (reference computes in fp32) — write fp32 directly.
  gemm_bt<float><<<dim3(32, 16), 256, 0, stream>>>(at_bf, Wo, (float*)d_out, 2048, 4096, 4096);
}

// Round 7
// 653.188 us; speedup vs baseline: 1.4483x; 1.4483x over previous
//
#include <hip/hip_runtime.h>
#include <hip/hip_bf16.h>

typedef __bf16 bf16;
typedef __attribute__((ext_vector_type(8))) __bf16 bf16x8;
typedef __attribute__((ext_vector_type(2))) __bf16 bf16x2;
typedef __attribute__((ext_vector_type(4))) float f32x4;

#define GLL16(g, l)                                                        \
  __builtin_amdgcn_global_load_lds(                                        \
      (const __attribute__((address_space(1))) unsigned int*)(g),          \
      (__attribute__((address_space(3))) unsigned int*)(l), 16, 0, 0)

// ---------------------------------------------------------------- convert
__global__ void cvt_f32_bf16(const float* __restrict__ in,
                             bf16* __restrict__ out, long n) {
  long i = ((long)blockIdx.x * blockDim.x + threadIdx.x) * 8;
  if (i >= n) return;
  f32x4 a = *reinterpret_cast<const f32x4*>(in + i);
  f32x4 b = *reinterpret_cast<const f32x4*>(in + i + 4);
  bf16x8 o;
  o[0] = (bf16)a[0]; o[1] = (bf16)a[1]; o[2] = (bf16)a[2]; o[3] = (bf16)a[3];
  o[4] = (bf16)b[0]; o[5] = (bf16)b[1]; o[6] = (bf16)b[2]; o[7] = (bf16)b[3];
  *reinterpret_cast<bf16x8*>(out + i) = o;
}

// ---------------------------------------------------------------- GEMM
// C[M][N] = A[M][K] * B[N][K]^T (bf16 in, fp32 accum), 128x128 tile,
// 4 waves, global_load_lds width-16, double-buffered (round-1 validated).
template <typename CT>
__global__ __launch_bounds__(256)
void gemm_bt(const bf16* __restrict__ A, const bf16* __restrict__ B,
             CT* __restrict__ C, int M, int N, int K) {
  __shared__ __align__(16) bf16 As[2][4096];  // [128][32]
  __shared__ __align__(16) bf16 Bs[2][4096];
  const int t = threadIdx.x;
  const int lane = t & 63;
  const int w = t >> 6;
  const int wr = w >> 1, wc = w & 1;
  const int bm = blockIdx.y * 128, bn = blockIdx.x * 128;
  const int fr = lane & 15, fg = lane >> 4;

  const int sr = t >> 2;        // staging row 0..63
  const int sc = (t & 3) * 8;   // staging col
  const bf16* gA = A + (long)(bm + sr) * K + sc;
  const bf16* gB = B + (long)(bn + sr) * K + sc;
  const long rowK64 = (long)64 * K;

  f32x4 acc[4][4];
#pragma unroll
  for (int m = 0; m < 4; m++)
#pragma unroll
    for (int n = 0; n < 4; n++) acc[m][n] = (f32x4){0.f, 0.f, 0.f, 0.f};

  {  // prologue: stage k0=0 into buffer 0
    bf16* lA = &As[0][t * 8];
    bf16* lB = &Bs[0][t * 8];
    GLL16(gA, lA); GLL16(gA + rowK64, lA + 2048);
    GLL16(gB, lB); GLL16(gB + rowK64, lB + 2048);
  }
  int cur = 0;
  for (int k0 = 0; k0 < K; k0 += 32) {
    __syncthreads();  // buf[cur] staged (vmcnt drained), prev reads done
    if (k0 + 32 < K) {
      const bf16* gA2 = gA + k0 + 32;
      const bf16* gB2 = gB + k0 + 32;
      bf16* lA = &As[cur ^ 1][t * 8];
      bf16* lB = &Bs[cur ^ 1][t * 8];
      GLL16(gA2, lA); GLL16(gA2 + rowK64, lA + 2048);
      GLL16(gB2, lB); GLL16(gB2 + rowK64, lB + 2048);
    }
    bf16x8 af[4], bfr[4];
#pragma unroll
    for (int m = 0; m < 4; m++)
      af[m] = *reinterpret_cast<const bf16x8*>(
          &As[cur][(wr * 64 + m * 16 + fr) * 32 + fg * 8]);
#pragma unroll
    for (int n = 0; n < 4; n++)
      bfr[n] = *reinterpret_cast<const bf16x8*>(
          &Bs[cur][(wc * 64 + n * 16 + fr) * 32 + fg * 8]);
#pragma unroll
    for (int m = 0; m < 4; m++)
#pragma unroll
      for (int n = 0; n < 4; n++)
        acc[m][n] =
            __builtin_amdgcn_mfma_f32_16x16x32_bf16(af[m], bfr[n], acc[m][n], 0, 0, 0);
    cur ^= 1;
  }
#pragma unroll
  for (int m = 0; m < 4; m++) {
#pragma unroll
    for (int n = 0; n < 4; n++) {
      const int row0 = bm + wr * 64 + m * 16 + fg * 4;
      const int col = bn + wc * 64 + n * 16 + fr;
#pragma unroll
      for (int j = 0; j < 4; j++)
        C[(long)(row0 + j) * N + col] = (CT)acc[m][n][j];
    }
  }
}

// ---------------------------------------------------------------- RoPE
__global__ void rope_kernel(bf16* __restrict__ q, bf16* __restrict__ k,
                            const int* __restrict__ pos_ids) {
  int idx = blockIdx.x * blockDim.x + threadIdx.x;  // 2048*40*64
  int s = idx / 2560;
  int rem = idx % 2560;
  int hh = rem >> 6;
  int dp = rem & 63;
  float p = (float)pos_ids[s];
  float freq = p * exp2f(-(float)dp * 0.20762050593046025f);
  float cs, sn;
  sincosf(freq, &sn, &cs);
  bf16* base = (hh < 32) ? (q + (long)s * 4096 + hh * 128)
                         : (k + (long)s * 1024 + (hh - 32) * 128);
  float x1 = (float)base[dp], x2 = (float)base[dp + 64];
  base[dp] = (bf16)(x1 * cs - x2 * sn);
  base[dp + 64] = (bf16)(x2 * cs + x1 * sn);
}

// ---------------------------------------------------------------- attention
// q:(2048,4096) k,v:(2048,1024) out:(2048,4096), GQA 4:1, causal
__global__ __launch_bounds__(256)
void attn_fwd(const bf16* __restrict__ qg, const bf16* __restrict__ kg,
              const bf16* __restrict__ vg, bf16* __restrict__ og) {
  const int h = blockIdx.y;
  // reversed dispatch: heaviest causal tiles first -> better makespan
  const int q0 = (gridDim.x - 1 - blockIdx.x) * 64;
  const int kvh = h >> 2;
  __shared__ __align__(16) bf16 Ks[32 * 128];    // [kv][d], XOR-swizzled
  __shared__ __align__(16) bf16 Vt[128 * 40];    // [d][kv], pitch 40
  __shared__ __align__(16) bf16 Pl[4][16 * 40];  // per-wave P, pitch 40
  const int t = threadIdx.x, lane = t & 63, w = t >> 6;
  const int fr = lane & 15, fg = lane >> 4;
  const int qrow = q0 + w * 16 + fr;

  bf16x8 aq[4];
#pragma unroll
  for (int c = 0; c < 4; c++)
    aq[c] = *reinterpret_cast<const bf16x8*>(
        &qg[(long)qrow * 4096 + h * 128 + c * 32 + fg * 8]);

  f32x4 oacc[8];
#pragma unroll
  for (int n = 0; n < 8; n++) oacc[n] = (f32x4){0.f, 0.f, 0.f, 0.f};
  float mrow[4], lrow[4];
#pragma unroll
  for (int j = 0; j < 4; j++) { mrow[j] = -INFINITY; lrow[j] = 0.f; }
  const float scale = 0.08838834764831845f;

  const int krow = t >> 3, kcol = (t & 7) * 16;  // K staging map
  const int ksw = (krow & 7) << 3;               // K swizzle (elements)
  const int vkv = (t & 15) * 2, vdb = (t >> 4) * 8;  // V staging: 2 kv x 8 d

  for (int kv0 = 0; kv0 < q0 + 64; kv0 += 32) {
    {  // stage K tile [32][128], reg-staged, XOR-swizzled
      const bf16* gk = &kg[(long)(kv0 + krow) * 1024 + kvh * 128 + kcol];
      bf16x8 ka = *reinterpret_cast<const bf16x8*>(gk);
      bf16x8 kb = *reinterpret_cast<const bf16x8*>(gk + 8);
      *reinterpret_cast<bf16x8*>(&Ks[krow * 128 + (kcol ^ ksw)]) = ka;
      *reinterpret_cast<bf16x8*>(&Ks[krow * 128 + ((kcol + 8) ^ ksw)]) = kb;
    }
    {  // stage V transposed: Vt[d][kv], kv-pairs packed as b32 writes
      const bf16* gv = &vg[(long)(kv0 + vkv) * 1024 + kvh * 128 + vdb];
      bf16x8 va = *reinterpret_cast<const bf16x8*>(gv);
      bf16x8 vb = *reinterpret_cast<const bf16x8*>(gv + 1024);
#pragma unroll
      for (int j = 0; j < 8; j++) {
        bf16x2 pr; pr[0] = va[j]; pr[1] = vb[j];
        *reinterpret_cast<bf16x2*>(&Vt[(vdb + j) * 40 + vkv]) = pr;
      }
    }
    __syncthreads();

    // S = Q K^T  (16 q-rows x 32 kv)
    f32x4 sacc[2];
    sacc[0] = (f32x4){0.f, 0.f, 0.f, 0.f};
    sacc[1] = (f32x4){0.f, 0.f, 0.f, 0.f};
#pragma unroll
    for (int c = 0; c < 2; c++)
#pragma unroll
      for (int kc = 0; kc < 4; kc++) {
        const int row = c * 16 + fr;
        bf16x8 bk = *reinterpret_cast<const bf16x8*>(
            &Ks[row * 128 + ((kc * 32 + fg * 8) ^ ((row & 7) << 3))]);
        sacc[c] = __builtin_amdgcn_mfma_f32_16x16x32_bf16(aq[kc], bk, sacc[c], 0, 0, 0);
      }

    // online softmax (rows live in 16-lane groups)
    float pv[2][4];
#pragma unroll
    for (int j = 0; j < 4; j++) {
      const int qp = q0 + w * 16 + fg * 4 + j;
      float s0 = sacc[0][j] * scale, s1 = sacc[1][j] * scale;
      if (kv0 + fr > qp) s0 = -INFINITY;
      if (kv0 + 16 + fr > qp) s1 = -INFINITY;
      float rmax = fmaxf(s0, s1);
#pragma unroll
      for (int off = 1; off < 16; off <<= 1)
        rmax = fmaxf(rmax, __shfl_xor(rmax, off, 64));
      float mnew = fmaxf(mrow[j], rmax);
      float alpha = __expf(mrow[j] - mnew);
      mrow[j] = mnew;
      float p0 = __expf(s0 - mnew), p1 = __expf(s1 - mnew);
      float rsum = p0 + p1;
#pragma unroll
      for (int off = 1; off < 16; off <<= 1) rsum += __shfl_xor(rsum, off, 64);
      lrow[j] = lrow[j] * alpha + rsum;
#pragma unroll
      for (int n = 0; n < 8; n++) oacc[n][j] *= alpha;
      pv[0][j] = p0; pv[1][j] = p1;
    }
    // P -> LDS (bf16), repack into A-fragment layout
#pragma unroll
    for (int j = 0; j < 4; j++) {
      Pl[w][(fg * 4 + j) * 40 + fr] = (bf16)pv[0][j];
      Pl[w][(fg * 4 + j) * 40 + 16 + fr] = (bf16)pv[1][j];
    }
    bf16x8 ap = *reinterpret_cast<const bf16x8*>(&Pl[w][fr * 40 + fg * 8]);
#pragma unroll
    for (int n = 0; n < 8; n++) {
      bf16x8 bv = *reinterpret_cast<const bf16x8*>(&Vt[(n * 16 + fr) * 40 + fg * 8]);
      oacc[n] = __builtin_amdgcn_mfma_f32_16x16x32_bf16(ap, bv, oacc[n], 0, 0, 0);
    }
    __syncthreads();
  }

#pragma unroll
  for (int n = 0; n < 8; n++) {
#pragma unroll
    for (int j = 0; j < 4; j++) {
      const int row = q0 + w * 16 + fg * 4 + j;
      const int col = h * 128 + n * 16 + fr;
      og[(long)row * 4096 + col] = (bf16)(oacc[n][j] / lrow[j]);
    }
  }
}

// ---------------------------------------------------------------- launch
extern "C" void kernel_launch(void* const* d_in, const int* in_sizes, int n_in,
                              void* d_out, int out_size, void* d_ws,
                              size_t ws_size, hipStream_t stream) {
  const float* hs = (const float*)d_in[0];
  const int* pos = (const int*)d_in[2];
  const float* Wq = (const float*)d_in[3];
  const float* Wk = (const float*)d_in[4];
  const float* Wv = (const float*)d_in[5];
  const float* Wo = (const float*)d_in[6];

  // ws layout (126 MB, round-1-demonstrated safe):
  char* ws = (char*)d_ws;
  bf16* h_bf  = (bf16*)(ws);                 // 16 MB
  bf16* wq_bf = (bf16*)(ws + 16777216L);     // 33.5 MB
  bf16* wk_bf = (bf16*)(ws + 50331648L);     // 8.4 MB
  bf16* wv_bf = (bf16*)(ws + 58720256L);     // 8.4 MB
  bf16* wo_bf = (bf16*)(ws + 67108864L);     // 33.5 MB
  bf16* q_bf  = (bf16*)(ws + 100663296L);    // 16 MB
  bf16* k_bf  = (bf16*)(ws + 117440512L);    // 4 MB
  bf16* v_bf  = (bf16*)(ws + 121634816L);    // 4 MB
  bf16* at_bf = h_bf;  // alias: h_bf dead after V projection

  auto cvtN = [&](const float* src, bf16* dst, long n) {
    cvt_f32_bf16<<<dim3((unsigned)(n / 2048)), 256, 0, stream>>>(src, dst, n);
  };
  cvtN(hs, h_bf, 8388608L);
  cvtN(Wq, wq_bf, 16777216L);
  cvtN(Wk, wk_bf, 4194304L);
  cvtN(Wv, wv_bf, 4194304L);
  cvtN(Wo, wo_bf, 16777216L);

  gemm_bt<bf16><<<dim3(32, 16), 256, 0, stream>>>(h_bf, wq_bf, q_bf, 2048, 4096, 4096);
  gemm_bt<bf16><<<dim3(8, 16), 256, 0, stream>>>(h_bf, wk_bf, k_bf, 2048, 1024, 4096);
  gemm_bt<bf16><<<dim3(8, 16), 256, 0, stream>>>(h_bf, wv_bf, v_bf, 2048, 1024, 4096);

  rope_kernel<<<dim3(20480), 256, 0, stream>>>(q_bf, k_bf, pos);

  attn_fwd<<<dim3(32, 32), 256, 0, stream>>>(q_bf, k_bf, v_bf, at_bf);

  // d_out is FLOAT32 — final projection writes fp32 directly.
  gemm_bt<float><<<dim3(32, 16), 256, 0, stream>>>(at_bf, wo_bf, (float*)d_out, 2048, 4096, 4096);
}